// Round 6
// baseline (1176.042 us; speedup 1.0000x reference)
//
#include <hip/hip_runtime.h>
#include <hip/hip_bf16.h>

#define NN 50000
#define D 128
#define RR 4
#define NNZ 800000
#define NCHUNK 196            // ceil(NN/256)

typedef float v2f    __attribute__((ext_vector_type(2)));
typedef float f32x4  __attribute__((ext_vector_type(4)));
typedef short bf16x8 __attribute__((ext_vector_type(8)));

static __device__ __forceinline__ unsigned short f2b(float f)
{
    __hip_bfloat16 h = __float2bfloat16(f);      // RNE
    return *reinterpret_cast<unsigned short*>(&h);
}
static __device__ __forceinline__ float b2f(unsigned short u)
{
    union { unsigned u32; float f; } v; v.u32 = ((unsigned)u) << 16; return v.f;
}

// ============================ CSR build =====================================
__global__ __launch_bounds__(256) void hist_kernel(
    const int* __restrict__ rows, int* __restrict__ cnt)
{
    const int r = blockIdx.y;
    const int e = blockIdx.x * 256 + threadIdx.x;      // NNZ = 3125*256 exact
    atomicAdd(&cnt[r * NN + rows[(size_t)r * NNZ + e]], 1);
}

__global__ __launch_bounds__(256) void scanA_kernel(
    const int* __restrict__ cnt, int* __restrict__ bsum)
{
    const int r = blockIdx.y, bx = blockIdx.x, t = threadIdx.x;
    const int idx = bx * 256 + t;
    int v = (idx < NN) ? cnt[r * NN + idx] : 0;
#pragma unroll
    for (int off = 32; off; off >>= 1) v += __shfl_xor(v, off);
    __shared__ int ws4[4];
    if ((t & 63) == 0) ws4[t >> 6] = v;
    __syncthreads();
    if (t == 0) bsum[r * NCHUNK + bx] = ws4[0] + ws4[1] + ws4[2] + ws4[3];
}

__global__ __launch_bounds__(256) void scanB_kernel(int* __restrict__ bsum)
{
    __shared__ int s[256];
    const int t = threadIdx.x;
    for (int r = 0; r < RR; ++r) {
        int v = (t < NCHUNK) ? bsum[r * NCHUNK + t] : 0;
        s[t] = v;
        __syncthreads();
        for (int off = 1; off < 256; off <<= 1) {
            int u = (t >= off) ? s[t - off] : 0;
            __syncthreads();
            s[t] += u;
            __syncthreads();
        }
        if (t < NCHUNK) bsum[r * NCHUNK + t] = s[t] - v;   // exclusive
        __syncthreads();
    }
}

__global__ __launch_bounds__(256) void scanC_kernel(
    const int* __restrict__ cnt, const int* __restrict__ bsum,
    int* __restrict__ rowptr, int* __restrict__ cursor)
{
    const int r = blockIdx.y, bx = blockIdx.x, t = threadIdx.x;
    const int idx = bx * 256 + t;
    int v = (idx < NN) ? cnt[r * NN + idx] : 0;
    __shared__ int s[256];
    s[t] = v;
    __syncthreads();
    for (int off = 1; off < 256; off <<= 1) {
        int u = (t >= off) ? s[t - off] : 0;
        __syncthreads();
        s[t] += u;
        __syncthreads();
    }
    const int excl = bsum[r * NCHUNK + bx] + s[t] - v;
    if (idx <= NN) rowptr[r * (NN + 1) + idx] = excl;
    if (idx < NN)  cursor[r * NN + idx] = excl;
}

__global__ __launch_bounds__(256) void fill_kernel(
    const int* __restrict__ rows, const int* __restrict__ cols,
    int* __restrict__ cursor, int* __restrict__ perm)
{
    const int r = blockIdx.y;
    const int e = blockIdx.x * 256 + threadIdx.x;
    const int row = rows[(size_t)r * NNZ + e];
    const int pos = atomicAdd(&cursor[r * NN + row], 1);
    perm[(size_t)r * NNZ + pos] = cols[(size_t)r * NNZ + e];
}

// ============================ W split to bf16 hi/lo =========================
// wh/wl[jg*128+k]: jg<128 -> W_self[jg][k], else W_rings flat row jg-128
__global__ __launch_bounds__(256) void convw_kernel(
    const float* __restrict__ Wself, const float* __restrict__ Wrings,
    unsigned short* __restrict__ wh, unsigned short* __restrict__ wl)
{
    int idx = blockIdx.x * 256 + threadIdx.x;    // 81920 elements
    int jg = idx >> 7, k = idx & 127;
    float f = (jg < 128) ? Wself[(size_t)jg * 128 + k]
                         : Wrings[(size_t)(jg - 128) * 128 + k];
    unsigned short hi = f2b(f);
    wh[idx] = hi;
    wl[idx] = f2b(f - b2f(hi));
}

// WC/WD transposed + split: wct_h[col*128+k] = bf16(WC[k][col]), etc.
__global__ __launch_bounds__(256) void convt_kernel(
    const float* __restrict__ WC, const float* __restrict__ WD,
    unsigned short* __restrict__ wct_h, unsigned short* __restrict__ wct_l,
    unsigned short* __restrict__ wdt_h, unsigned short* __restrict__ wdt_l)
{
    int idx = blockIdx.x * 256 + threadIdx.x;     // 16384, coalesced read
    int kk = idx >> 7, col = idx & 127;
    float c = WC[idx];
    float d = WD[idx];
    unsigned short ch = f2b(c), dh = f2b(d);
    wct_h[col * 128 + kk] = ch;
    wct_l[col * 128 + kk] = f2b(c - b2f(ch));
    wdt_h[col * 128 + kk] = dh;
    wdt_l[col * 128 + kk] = f2b(d - b2f(dh));
}

// ============================ CSR gather (pre-GEMM) =========================
// y[(ring-r0)][row][:] = sum over edges (row,col) of ring: odn[col] * x[col][:]
// One wave per (row, ring). Lane halves process alternate edges (2 edges per
// load instruction, float4/lane), unroll 4 -> 8 edges in flight.
__global__ __launch_bounds__(256) void gather2_kernel(
    const float* __restrict__ x, const float* __restrict__ odn,
    const int* __restrict__ rp, const int* __restrict__ pm,
    float* __restrict__ y, int r0)
{
    const int cr = blockIdx.y + r0;                 // CSR ring index
    const int t = threadIdx.x;
    const int row = blockIdx.x * 4 + (t >> 6);      // 12500*4 = 50000 exact
    const int l  = t & 63;
    const int h  = l >> 5;                          // edge parity (0/1)
    const int dq = l & 31;                          // float4 index in row
    const int* rpr = rp + (size_t)cr * (NN + 1);
    const int s = rpr[row], e = rpr[row + 1];
    const int* pmr = pm + (size_t)cr * NNZ;

    f32x4 acc = {0.f, 0.f, 0.f, 0.f};
    int i = s;
    for (; i + 8 <= e; i += 8) {
        int c0 = pmr[i + h],     c1 = pmr[i + 2 + h];
        int c2 = pmr[i + 4 + h], c3 = pmr[i + 6 + h];
        float o0 = odn[c0], o1 = odn[c1], o2 = odn[c2], o3 = odn[c3];
        f32x4 v0 = *(const f32x4*)&x[(size_t)c0 * D + dq * 4];
        f32x4 v1 = *(const f32x4*)&x[(size_t)c1 * D + dq * 4];
        f32x4 v2 = *(const f32x4*)&x[(size_t)c2 * D + dq * 4];
        f32x4 v3 = *(const f32x4*)&x[(size_t)c3 * D + dq * 4];
        acc += v0 * o0 + v1 * o1 + v2 * o2 + v3 * o3;
    }
    for (; i + h < e; i += 2) {
        int c = pmr[i + h];
        acc += (*(const f32x4*)&x[(size_t)c * D + dq * 4]) * odn[c];
    }
#pragma unroll
    for (int j = 0; j < 4; ++j) acc[j] += __shfl_xor(acc[j], 32);
    if (h == 0)
        *(f32x4*)&y[((size_t)blockIdx.y * NN + row) * D + dq * 4] = acc;
}

// ============================ 5-slab split-bf16 MFMA GEMM ===================
// Slab s (blockIdx.y + s0): A = (s==0 ? x : y[s-1-r0]);  cols jg = s*128+local.
// out[n][jg] = sum_k A[n][k] * W_all[jg][k];  product = ah*Wh + al*Wh + ah*Wl.
// Frag layout (16x16x32): A: row=l&15, k=(l>>4)*8+j ; B: col=l&15, same k.
// C: col=l&15, row=(l>>4)*4+q  [m89-verified]
__global__ __launch_bounds__(256) void gemm5_kernel(
    const float* __restrict__ x, const float* __restrict__ y,
    const unsigned short* __restrict__ wh, const unsigned short* __restrict__ wl,
    float* __restrict__ out, int s0, int r0)
{
    const int s = s0 + blockIdx.y;
    const float* A = (s == 0) ? x : y + (size_t)(s - 1 - r0) * NN * D;
    const int t = threadIdx.x;
    const int w = t >> 6, l = t & 63;
    const int lr = l & 15, lk = l >> 4;
    const int n0 = blockIdx.x * 16;

    bf16x8 ah[4], al[4];
    const float* xr = A + (size_t)(n0 + lr) * D + lk * 8;
#pragma unroll
    for (int ks = 0; ks < 4; ++ks) {
        float4 v0 = *(const float4*)(xr + ks * 32);
        float4 v1 = *(const float4*)(xr + ks * 32 + 4);
        float f[8] = {v0.x, v0.y, v0.z, v0.w, v1.x, v1.y, v1.z, v1.w};
#pragma unroll
        for (int j = 0; j < 8; ++j) {
            unsigned short hi = f2b(f[j]);
            ah[ks][j] = (short)hi;
            al[ks][j] = (short)f2b(f[j] - b2f(hi));
        }
    }

#pragma unroll
    for (int j = 0; j < 2; ++j) {
        const int ctl = w + 4 * j;                  // 0..7 local col-tile
        const int jg  = s * 128 + ctl * 16 + lr;    // global out column
        f32x4 acc = {0.f, 0.f, 0.f, 0.f};
#pragma unroll
        for (int ks = 0; ks < 4; ++ks) {
            bf16x8 bhv = *(const bf16x8*)&wh[(size_t)jg * D + ks * 32 + lk * 8];
            bf16x8 blv = *(const bf16x8*)&wl[(size_t)jg * D + ks * 32 + lk * 8];
            acc = __builtin_amdgcn_mfma_f32_16x16x32_bf16(ah[ks], bhv, acc, 0, 0, 0);
            acc = __builtin_amdgcn_mfma_f32_16x16x32_bf16(al[ks], bhv, acc, 0, 0, 0);
            acc = __builtin_amdgcn_mfma_f32_16x16x32_bf16(ah[ks], blv, acc, 0, 0, 0);
        }
#pragma unroll
        for (int q = 0; q < 4; ++q) {
            int n = n0 + lk * 4 + q;
            out[(size_t)n * 640 + jg] = acc[q];
        }
    }
}

// ============================ interaction (MFMA) ============================
__device__ __forceinline__ int sidx(int r, int s)
{
    if (r > s) { int t = r; r = s; s = t; }
    return r * 5 + s - (r * (r + 1)) / 2;
}

__global__ __launch_bounds__(512, 4) void interact2_kernel(
    float* __restrict__ z,
    const unsigned short* __restrict__ wct_h, const unsigned short* __restrict__ wct_l,
    const unsigned short* __restrict__ wdt_h, const unsigned short* __restrict__ wdt_l,
    const float* __restrict__ att_w, const float* __restrict__ att_b,
    const float* __restrict__ idn)
{
    __shared__ float SB[2 * 5 * 16 * 128];    // 80 KB

    const int t  = threadIdx.x;
    const int w  = t >> 6;
    const int l  = t & 63;
    const int lr = l & 15;
    const int lk = l >> 4;
    const int n0 = blockIdx.x * 16;

    const int mm = w >> 2;
    const int nq = w & 3;
    const unsigned short* bhp = mm ? wdt_h : wct_h;
    const unsigned short* blp = mm ? wdt_l : wct_l;

    f32x4 acc[5][2];
#pragma unroll
    for (int mt = 0; mt < 5; ++mt) {
        acc[mt][0] = (f32x4){0.f, 0.f, 0.f, 0.f};
        acc[mt][1] = (f32x4){0.f, 0.f, 0.f, 0.f};
    }

#pragma unroll
    for (int mt = 0; mt < 5; ++mt) {
        bf16x8 ah[4], al[4];
        const float* ap = z + (size_t)(n0 + lr) * 640 + mt * 128 + lk * 8;
#pragma unroll
        for (int ks = 0; ks < 4; ++ks) {
            float4 v0 = *(const float4*)(ap + ks * 32);
            float4 v1 = *(const float4*)(ap + ks * 32 + 4);
            float f[8] = {v0.x, v0.y, v0.z, v0.w, v1.x, v1.y, v1.z, v1.w};
#pragma unroll
            for (int j = 0; j < 8; ++j) {
                unsigned short hi = f2b(f[j]);
                ah[ks][j] = (short)hi;
                al[ks][j] = (short)f2b(f[j] - b2f(hi));
            }
        }
#pragma unroll
        for (int nt = 0; nt < 2; ++nt) {
            const int col = nq * 32 + nt * 16 + lr;
#pragma unroll
            for (int ks = 0; ks < 4; ++ks) {
                bf16x8 vh = *(const bf16x8*)&bhp[(size_t)col * 128 + ks * 32 + lk * 8];
                bf16x8 vl = *(const bf16x8*)&blp[(size_t)col * 128 + ks * 32 + lk * 8];
                acc[mt][nt] = __builtin_amdgcn_mfma_f32_16x16x32_bf16(ah[ks], vh, acc[mt][nt], 0, 0, 0);
                acc[mt][nt] = __builtin_amdgcn_mfma_f32_16x16x32_bf16(al[ks], vh, acc[mt][nt], 0, 0, 0);
                acc[mt][nt] = __builtin_amdgcn_mfma_f32_16x16x32_bf16(ah[ks], vl, acc[mt][nt], 0, 0, 0);
            }
        }
    }

#pragma unroll
    for (int mt = 0; mt < 5; ++mt)
#pragma unroll
        for (int nt = 0; nt < 2; ++nt) {
            const int col = nq * 32 + nt * 16 + lr;
#pragma unroll
            for (int q = 0; q < 4; ++q) {
                const int nd = lk * 4 + q;
                SB[(((mm * 5 + mt) * 16) + nd) * 128 + col] = acc[mt][nt][q];
            }
        }
    __syncthreads();

#pragma unroll
    for (int ii = 0; ii < 2; ++ii) {
        const int nd = w + ii * 8;
        const int n  = n0 + nd;
        const float nf = idn[n];

        v2f ar[5], dr[5];
#pragma unroll
        for (int r = 0; r < 5; ++r) {
            ar[r] = *(const v2f*)&SB[((r * 16) + nd) * 128 + 2 * l] * nf;
            dr[r] = *(const v2f*)&SB[(((5 + r) * 16) + nd) * 128 + 2 * l] * nf;
        }

        float pc[15], pd[15];
        {
            int k = 0;
#pragma unroll
            for (int r = 0; r < 5; ++r)
#pragma unroll
                for (int s = r; s < 5; ++s, ++k) {
                    v2f qc = ar[r] * ar[s];
                    v2f qd = dr[r] * dr[s];
                    float vc = qc.x + qc.y;
                    float vd = qd.x + qd.y;
#pragma unroll
                    for (int off = 32; off; off >>= 1) {
                        vc += __shfl_xor(vc, off);
                        vd += __shfl_xor(vd, off);
                    }
                    pc[k] = vc; pd[k] = vd;
                }
        }

        v2f zcom[5], zdis[5];
#pragma unroll
        for (int r = 0; r < 5; ++r) {
            float sc[5], m = -1e30f;
#pragma unroll
            for (int s = 0; s < 5; ++s) { sc[s] = pc[sidx(r, s)]; m = fmaxf(m, sc[s]); }
            float e[5], se = 0.f;
#pragma unroll
            for (int s = 0; s < 5; ++s) { e[s] = __expf(sc[s] - m); se += e[s]; }
            float inv = 1.f / se;
            v2f a2 = (v2f)0.f;
#pragma unroll
            for (int s = 0; s < 5; ++s) a2 += ar[s] * e[s];
            zcom[r] = a2 * inv;

            float qq = pd[sidx(r, r)];
            float sd[5], md = -1e30f;
#pragma unroll
            for (int s = 0; s < 5; ++s) { sd[s] = qq - pd[sidx(r, s)]; md = fmaxf(md, sd[s]); }
            float ed[5], sed = 0.f;
#pragma unroll
            for (int s = 0; s < 5; ++s) { ed[s] = __expf(sd[s] - md); sed += ed[s]; }
            float invd = 1.f / sed;
            v2f d2 = (v2f)0.f;
#pragma unroll
            for (int s = 0; s < 5; ++s) d2 += dr[s] * ed[s];
            zdis[r] = dr[r] - d2 * invd;       // sum_s a*(zd_r - zd_s)
        }

        v2f p2 = (v2f)0.f;
#pragma unroll
        for (int r = 0; r < 5; ++r) {
            p2 += (*(const v2f*)&att_w[r * 128 + 2 * l]) * zcom[r];
            p2 += (*(const v2f*)&att_w[640 + r * 128 + 2 * l]) * zdis[r];
        }
        float part = p2.x + p2.y;
#pragma unroll
        for (int off = 32; off; off >>= 1) part += __shfl_xor(part, off);
        const float beta = 1.f / (1.f + __expf(-(part + att_b[0])));
        const float omb  = 1.f - beta;

#pragma unroll
        for (int r = 0; r < 5; ++r) {
            v2f o = zcom[r] * beta + zdis[r] * omb;
            *(v2f*)&z[(size_t)n * 640 + r * 128 + 2 * l] = o;
        }
    }
}

// ============================ launch ========================================
extern "C" void kernel_launch(void* const* d_in, const int* in_sizes, int n_in,
                              void* d_out, int out_size, void* d_ws, size_t ws_size,
                              hipStream_t stream)
{
    const float* x      = (const float*)d_in[0];
    const float* W_self = (const float*)d_in[1];
    const float* W_ring = (const float*)d_in[2];
    const float* WC     = (const float*)d_in[3];
    const float* WD     = (const float*)d_in[4];
    const float* att_w  = (const float*)d_in[5];
    const float* att_b  = (const float*)d_in[6];
    const float* odn    = (const float*)d_in[7];
    const float* idn    = (const float*)d_in[8];
    const int*   rows   = (const int*)d_in[9];
    const int*   cols   = (const int*)d_in[10];
    float* out = (float*)d_out;

    // ---- workspace layout ----
    const size_t wb_sz  = (size_t)640 * 128 * 2;        // wh, wl
    const size_t wt_sz  = (size_t)128 * 128 * 2;        // wct_h/l, wdt_h/l
    const size_t y1_sz  = (size_t)NN * D * 4;           // 25.6 MB per ring
    const size_t cnt_sz = (size_t)RR * NN * 4;
    const size_t rp_sz  = (size_t)RR * (NN + 1) * 4;
    const size_t cur_sz = (size_t)RR * NN * 4;
    const size_t bs_sz  = 4096;
    const size_t pm_sz  = (size_t)RR * NNZ * 4;
    const size_t fixed  = 2 * wb_sz + 4 * wt_sz + cnt_sz + rp_sz + cur_sz + bs_sz + pm_sz;
    const bool big = ws_size >= fixed + RR * y1_sz + 4096;   // ~118.2 MB
    // fallback path footprint ~41.3 MB (proven in rounds 1-2)

    char* p = (char*)d_ws;
    unsigned short* wh    = (unsigned short*)p; p += wb_sz;
    unsigned short* wl    = (unsigned short*)p; p += wb_sz;
    unsigned short* wct_h = (unsigned short*)p; p += wt_sz;
    unsigned short* wct_l = (unsigned short*)p; p += wt_sz;
    unsigned short* wdt_h = (unsigned short*)p; p += wt_sz;
    unsigned short* wdt_l = (unsigned short*)p; p += wt_sz;
    float* y    = (float*)p; p += (big ? RR : 1) * y1_sz;
    int* cnt    = (int*)p; p += cnt_sz;
    int* rowptr = (int*)p; p += rp_sz;
    int* cursor = (int*)p; p += cur_sz;
    int* bsum   = (int*)p; p += bs_sz;
    int* perm   = (int*)p;

    // ---- weight conversions (tiny) ----
    convw_kernel<<<320, 256, 0, stream>>>(W_self, W_ring, wh, wl);
    convt_kernel<<<64, 256, 0, stream>>>(WC, WD, wct_h, wct_l, wdt_h, wdt_l);

    // ---- CSR build ----
    hipMemsetAsync(cnt, 0, cnt_sz, stream);
    hist_kernel<<<dim3(NNZ / 256, RR), 256, 0, stream>>>(rows, cnt);
    scanA_kernel<<<dim3(NCHUNK, RR), 256, 0, stream>>>(cnt, bsum);
    scanB_kernel<<<1, 256, 0, stream>>>(bsum);
    scanC_kernel<<<dim3(NCHUNK, RR), 256, 0, stream>>>(cnt, bsum, rowptr, cursor);
    fill_kernel<<<dim3(NNZ / 256, RR), 256, 0, stream>>>(rows, cols, cursor, perm);

    if (big) {
        // gather all rings from x (odn folded per-edge), then one 5-slab GEMM
        gather2_kernel<<<dim3(NN / 4, RR), 256, 0, stream>>>(x, odn, rowptr, perm, y, 0);
        gemm5_kernel<<<dim3(NN / 16, 5), 256, 0, stream>>>(x, y, wh, wl, out, 0, 0);
    } else {
        // lean path: slab 0, then per-ring gather + GEMM reusing one y buffer
        gemm5_kernel<<<dim3(NN / 16, 1), 256, 0, stream>>>(x, y, wh, wl, out, 0, 0);
        for (int r = 0; r < RR; ++r) {
            gather2_kernel<<<dim3(NN / 4, 1), 256, 0, stream>>>(x, odn, rowptr, perm, y, r);
            gemm5_kernel<<<dim3(NN / 16, 1), 256, 0, stream>>>(x, y, wh, wl, out, r + 1, r);
        }
    }

    // ---- fused per-node interaction (in-place on d_out) ----
    interact2_kernel<<<NN / 16, 512, 0, stream>>>(out, wct_h, wct_l, wdt_h, wdt_l,
                                                  att_w, att_b, idn);
}

// Round 7
// 1007.642 us; speedup vs baseline: 1.1671x; 1.1671x over previous
//
#include <hip/hip_runtime.h>
#include <hip/hip_bf16.h>

#define NN 50000
#define D 128
#define RR 4
#define NNZ 800000
#define NCHUNK 196            // ceil(NN/256)

typedef float v2f    __attribute__((ext_vector_type(2)));
typedef float f32x4  __attribute__((ext_vector_type(4)));
typedef short bf16x8 __attribute__((ext_vector_type(8)));

static __device__ __forceinline__ unsigned short f2b(float f)
{
    __hip_bfloat16 h = __float2bfloat16(f);      // RNE
    return *reinterpret_cast<unsigned short*>(&h);
}
static __device__ __forceinline__ float b2f(unsigned short u)
{
    union { unsigned u32; float f; } v; v.u32 = ((unsigned)u) << 16; return v.f;
}

// ============================ CSR build =====================================
__global__ __launch_bounds__(256) void hist_kernel(
    const int* __restrict__ rows, int* __restrict__ cnt)
{
    const int r = blockIdx.y;
    const int e = blockIdx.x * 256 + threadIdx.x;      // NNZ = 3125*256 exact
    atomicAdd(&cnt[r * NN + rows[(size_t)r * NNZ + e]], 1);
}

__global__ __launch_bounds__(256) void scanA_kernel(
    const int* __restrict__ cnt, int* __restrict__ bsum)
{
    const int r = blockIdx.y, bx = blockIdx.x, t = threadIdx.x;
    const int idx = bx * 256 + t;
    int v = (idx < NN) ? cnt[r * NN + idx] : 0;
#pragma unroll
    for (int off = 32; off; off >>= 1) v += __shfl_xor(v, off);
    __shared__ int ws4[4];
    if ((t & 63) == 0) ws4[t >> 6] = v;
    __syncthreads();
    if (t == 0) bsum[r * NCHUNK + bx] = ws4[0] + ws4[1] + ws4[2] + ws4[3];
}

__global__ __launch_bounds__(256) void scanB_kernel(int* __restrict__ bsum)
{
    __shared__ int s[256];
    const int t = threadIdx.x;
    for (int r = 0; r < RR; ++r) {
        int v = (t < NCHUNK) ? bsum[r * NCHUNK + t] : 0;
        s[t] = v;
        __syncthreads();
        for (int off = 1; off < 256; off <<= 1) {
            int u = (t >= off) ? s[t - off] : 0;
            __syncthreads();
            s[t] += u;
            __syncthreads();
        }
        if (t < NCHUNK) bsum[r * NCHUNK + t] = s[t] - v;   // exclusive
        __syncthreads();
    }
}

__global__ __launch_bounds__(256) void scanC_kernel(
    const int* __restrict__ cnt, const int* __restrict__ bsum,
    int* __restrict__ rowptr, int* __restrict__ cursor)
{
    const int r = blockIdx.y, bx = blockIdx.x, t = threadIdx.x;
    const int idx = bx * 256 + t;
    int v = (idx < NN) ? cnt[r * NN + idx] : 0;
    __shared__ int s[256];
    s[t] = v;
    __syncthreads();
    for (int off = 1; off < 256; off <<= 1) {
        int u = (t >= off) ? s[t - off] : 0;
        __syncthreads();
        s[t] += u;
        __syncthreads();
    }
    const int excl = bsum[r * NCHUNK + bx] + s[t] - v;
    if (idx <= NN) rowptr[r * (NN + 1) + idx] = excl;
    if (idx < NN)  cursor[r * NN + idx] = excl;
}

__global__ __launch_bounds__(256) void fill_kernel(
    const int* __restrict__ rows, const int* __restrict__ cols,
    int* __restrict__ cursor, int* __restrict__ perm)
{
    const int r = blockIdx.y;
    const int e = blockIdx.x * 256 + threadIdx.x;
    const int row = rows[(size_t)r * NNZ + e];
    const int pos = atomicAdd(&cursor[r * NN + row], 1);
    perm[(size_t)r * NNZ + pos] = cols[(size_t)r * NNZ + e];
}

// ============================ W split to bf16 hi/lo =========================
__global__ __launch_bounds__(256) void convw_kernel(
    const float* __restrict__ Wself, const float* __restrict__ Wrings,
    unsigned short* __restrict__ wh, unsigned short* __restrict__ wl)
{
    int idx = blockIdx.x * 256 + threadIdx.x;    // 81920 elements
    int jg = idx >> 7, k = idx & 127;
    float f = (jg < 128) ? Wself[(size_t)jg * 128 + k]
                         : Wrings[(size_t)(jg - 128) * 128 + k];
    unsigned short hi = f2b(f);
    wh[idx] = hi;
    wl[idx] = f2b(f - b2f(hi));
}

// WC/WD transposed + split: wct_h[col*128+k] = bf16(WC[k][col]), etc.
__global__ __launch_bounds__(256) void convt_kernel(
    const float* __restrict__ WC, const float* __restrict__ WD,
    unsigned short* __restrict__ wct_h, unsigned short* __restrict__ wct_l,
    unsigned short* __restrict__ wdt_h, unsigned short* __restrict__ wdt_l)
{
    int idx = blockIdx.x * 256 + threadIdx.x;     // 16384, coalesced read
    int kk = idx >> 7, col = idx & 127;
    float c = WC[idx];
    float d = WD[idx];
    unsigned short ch = f2b(c), dh = f2b(d);
    wct_h[col * 128 + kk] = ch;
    wct_l[col * 128 + kk] = f2b(c - b2f(ch));
    wdt_h[col * 128 + kk] = dh;
    wdt_l[col * 128 + kk] = f2b(d - b2f(dh));
}

// ============================ CSR gather (pre-GEMM) =========================
// y[(ring-r0)][row][:] = sum over edges (row,col) of ring: odn[col] * x[col][:]
__global__ __launch_bounds__(256) void gather2_kernel(
    const float* __restrict__ x, const float* __restrict__ odn,
    const int* __restrict__ rp, const int* __restrict__ pm,
    float* __restrict__ y, int r0)
{
    const int cr = blockIdx.y + r0;
    const int t = threadIdx.x;
    const int row = blockIdx.x * 4 + (t >> 6);      // 12500*4 = 50000 exact
    const int l  = t & 63;
    const int h  = l >> 5;                          // edge parity (0/1)
    const int dq = l & 31;                          // float4 index in row
    const int* rpr = rp + (size_t)cr * (NN + 1);
    const int s = rpr[row], e = rpr[row + 1];
    const int* pmr = pm + (size_t)cr * NNZ;

    f32x4 acc = {0.f, 0.f, 0.f, 0.f};
    int i = s;
    for (; i + 8 <= e; i += 8) {
        int c0 = pmr[i + h],     c1 = pmr[i + 2 + h];
        int c2 = pmr[i + 4 + h], c3 = pmr[i + 6 + h];
        float o0 = odn[c0], o1 = odn[c1], o2 = odn[c2], o3 = odn[c3];
        f32x4 v0 = *(const f32x4*)&x[(size_t)c0 * D + dq * 4];
        f32x4 v1 = *(const f32x4*)&x[(size_t)c1 * D + dq * 4];
        f32x4 v2 = *(const f32x4*)&x[(size_t)c2 * D + dq * 4];
        f32x4 v3 = *(const f32x4*)&x[(size_t)c3 * D + dq * 4];
        acc += v0 * o0 + v1 * o1 + v2 * o2 + v3 * o3;
    }
    for (; i + h < e; i += 2) {
        int c = pmr[i + h];
        acc += (*(const f32x4*)&x[(size_t)c * D + dq * 4]) * odn[c];
    }
#pragma unroll
    for (int j = 0; j < 4; ++j) acc[j] += __shfl_xor(acc[j], 32);
    if (h == 0)
        *(f32x4*)&y[((size_t)blockIdx.y * NN + row) * D + dq * 4] = acc;
}

// ============================ 5-slab GEMM (lean fallback) ===================
__global__ __launch_bounds__(256) void gemm5_kernel(
    const float* __restrict__ x, const float* __restrict__ y,
    const unsigned short* __restrict__ wh, const unsigned short* __restrict__ wl,
    float* __restrict__ out, int s0, int r0)
{
    const int s = s0 + blockIdx.y;
    const float* A = (s == 0) ? x : y + (size_t)(s - 1 - r0) * NN * D;
    const int t = threadIdx.x;
    const int w = t >> 6, l = t & 63;
    const int lr = l & 15, lk = l >> 4;
    const int n0 = blockIdx.x * 16;

    bf16x8 ah[4], al[4];
    const float* xr = A + (size_t)(n0 + lr) * D + lk * 8;
#pragma unroll
    for (int ks = 0; ks < 4; ++ks) {
        float4 v0 = *(const float4*)(xr + ks * 32);
        float4 v1 = *(const float4*)(xr + ks * 32 + 4);
        float f[8] = {v0.x, v0.y, v0.z, v0.w, v1.x, v1.y, v1.z, v1.w};
#pragma unroll
        for (int j = 0; j < 8; ++j) {
            unsigned short hi = f2b(f[j]);
            ah[ks][j] = (short)hi;
            al[ks][j] = (short)f2b(f[j] - b2f(hi));
        }
    }

#pragma unroll
    for (int j = 0; j < 2; ++j) {
        const int ctl = w + 4 * j;
        const int jg  = s * 128 + ctl * 16 + lr;
        f32x4 acc = {0.f, 0.f, 0.f, 0.f};
#pragma unroll
        for (int ks = 0; ks < 4; ++ks) {
            bf16x8 bhv = *(const bf16x8*)&wh[(size_t)jg * D + ks * 32 + lk * 8];
            bf16x8 blv = *(const bf16x8*)&wl[(size_t)jg * D + ks * 32 + lk * 8];
            acc = __builtin_amdgcn_mfma_f32_16x16x32_bf16(ah[ks], bhv, acc, 0, 0, 0);
            acc = __builtin_amdgcn_mfma_f32_16x16x32_bf16(al[ks], bhv, acc, 0, 0, 0);
            acc = __builtin_amdgcn_mfma_f32_16x16x32_bf16(ah[ks], blv, acc, 0, 0, 0);
        }
#pragma unroll
        for (int q = 0; q < 4; ++q) {
            int n = n0 + lk * 4 + q;
            out[(size_t)n * 640 + jg] = acc[q];
        }
    }
}

// ============================ shared helpers ================================
__device__ __forceinline__ int sidx(int r, int s)
{
    if (r > s) { int t = r; r = s; s = t; }
    return r * 5 + s - (r * (r + 1)) / 2;
}

// ======================= FUSED z-GEMM + interaction =========================
// Block = 512 thr (8 waves) = 16 nodes. z-tile (16x640) never touches HBM.
// LDS plan (union, 80 KB total -> 2 blocks/CU):
//   [0,40960):  AH/AL   [80 rows][128] ushort, swz byte^=((row&7)<<4)   (phase A/B1)
//               ZH2/ZL2 same layout/swz, overwritten after barrier       (B1.5/B2)
//   [0,81920):  SB [160 rows][128] f32, swz byte^=(((row>>2)&3)<<4)     (B2.5/C)
__global__ __launch_bounds__(512, 4) void fused_kernel(
    const float* __restrict__ x, const float* __restrict__ y,
    const unsigned short* __restrict__ wh, const unsigned short* __restrict__ wl,
    const unsigned short* __restrict__ wct_h, const unsigned short* __restrict__ wct_l,
    const unsigned short* __restrict__ wdt_h, const unsigned short* __restrict__ wdt_l,
    const float* __restrict__ att_w, const float* __restrict__ att_b,
    const float* __restrict__ idn, float* __restrict__ out)
{
    __shared__ __align__(16) char LB[81920];

    const int t  = threadIdx.x;
    const int w  = t >> 6;
    const int l  = t & 63;
    const int lr = l & 15;
    const int lk = l >> 4;
    const int n0 = blockIdx.x * 16;

    // ---------------- phase A: split x-tile + 4 y-tiles into LDS ----------
#pragma unroll
    for (int i = 0; i < 5; ++i) {
        const int fi = i * 512 + t;            // float4 idx in [0,2560)
        const int e  = fi * 4;
        const int s  = e >> 11;                // slab 0..4
        const int nd = (e >> 7) & 15;
        const int k0 = e & 127;
        const float* src = (s == 0)
            ? &x[(size_t)(n0 + nd) * 128 + k0]
            : &y[((size_t)(s - 1) * NN + (n0 + nd)) * 128 + k0];
        f32x4 v = *(const f32x4*)src;
        const int row  = s * 16 + nd;
        const int boff = ((row * 128 + k0) * 2) ^ ((row & 7) << 4);
        ushort4 hv, lv;
        unsigned short h0 = f2b(v[0]), h1 = f2b(v[1]), h2 = f2b(v[2]), h3 = f2b(v[3]);
        hv.x = h0; hv.y = h1; hv.z = h2; hv.w = h3;
        lv.x = f2b(v[0] - b2f(h0)); lv.y = f2b(v[1] - b2f(h1));
        lv.z = f2b(v[2] - b2f(h2)); lv.w = f2b(v[3] - b2f(h3));
        *(ushort4*)(LB + boff)         = hv;
        *(ushort4*)(LB + 20480 + boff) = lv;
    }
    __syncthreads();

    // ---------------- B1: z-tile MFMA (wave w -> col-tiles ct=w+8j) --------
    f32x4 zacc[5];
#pragma unroll
    for (int j = 0; j < 5; ++j) zacc[j] = (f32x4){0.f, 0.f, 0.f, 0.f};

#pragma unroll
    for (int j = 0; j < 5; ++j) {
        const int jg = (w + 8 * j) * 16 + lr;          // W_all row, slab = j
#pragma unroll
        for (int ks = 0; ks < 4; ++ks) {
            const int arow  = j * 16 + lr;
            const int abyte = ((arow * 128 + ks * 32 + lk * 8) * 2) ^ ((arow & 7) << 4);
            bf16x8 ah = *(const bf16x8*)(LB + abyte);
            bf16x8 al = *(const bf16x8*)(LB + 20480 + abyte);
            bf16x8 bh = *(const bf16x8*)&wh[(size_t)jg * 128 + ks * 32 + lk * 8];
            bf16x8 bl = *(const bf16x8*)&wl[(size_t)jg * 128 + ks * 32 + lk * 8];
            zacc[j] = __builtin_amdgcn_mfma_f32_16x16x32_bf16(ah, bh, zacc[j], 0, 0, 0);
            zacc[j] = __builtin_amdgcn_mfma_f32_16x16x32_bf16(al, bh, zacc[j], 0, 0, 0);
            zacc[j] = __builtin_amdgcn_mfma_f32_16x16x32_bf16(ah, bl, zacc[j], 0, 0, 0);
        }
    }
    __syncthreads();   // all AH/AL reads done

    // ---------------- B1.5: split z accs into ZH2/ZL2 (same region) -------
    {
        const int k = w * 16 + lr;                     // z col within slab
#pragma unroll
        for (int j = 0; j < 5; ++j)
#pragma unroll
            for (int q = 0; q < 4; ++q) {
                const int nd  = lk * 4 + q;
                const int row = j * 16 + nd;
                const float zv = zacc[j][q];
                const unsigned short hi = f2b(zv);
                const unsigned short lo = f2b(zv - b2f(hi));
                const int boff = ((row * 128 + k) * 2) ^ ((row & 7) << 4);
                *(unsigned short*)(LB + boff)         = hi;
                *(unsigned short*)(LB + 20480 + boff) = lo;
            }
    }
    __syncthreads();

    // ---------------- B2: WC/WD matvec MFMA --------------------------------
    const int mm = w >> 2;
    const int nq = w & 3;
    const unsigned short* bhp = mm ? wdt_h : wct_h;
    const unsigned short* blp = mm ? wdt_l : wct_l;

    f32x4 acc2[5][2];
#pragma unroll
    for (int mt = 0; mt < 5; ++mt) {
        acc2[mt][0] = (f32x4){0.f, 0.f, 0.f, 0.f};
        acc2[mt][1] = (f32x4){0.f, 0.f, 0.f, 0.f};
    }

#pragma unroll
    for (int ks = 0; ks < 4; ++ks) {
        const int c0 = nq * 32 + lr;
        const int c1 = c0 + 16;
        bf16x8 bh0 = *(const bf16x8*)&bhp[(size_t)c0 * 128 + ks * 32 + lk * 8];
        bf16x8 bl0 = *(const bf16x8*)&blp[(size_t)c0 * 128 + ks * 32 + lk * 8];
        bf16x8 bh1 = *(const bf16x8*)&bhp[(size_t)c1 * 128 + ks * 32 + lk * 8];
        bf16x8 bl1 = *(const bf16x8*)&blp[(size_t)c1 * 128 + ks * 32 + lk * 8];
#pragma unroll
        for (int mt = 0; mt < 5; ++mt) {
            const int arow  = mt * 16 + lr;
            const int abyte = ((arow * 128 + ks * 32 + lk * 8) * 2) ^ ((arow & 7) << 4);
            bf16x8 zh = *(const bf16x8*)(LB + abyte);
            bf16x8 zl = *(const bf16x8*)(LB + 20480 + abyte);
            acc2[mt][0] = __builtin_amdgcn_mfma_f32_16x16x32_bf16(zh, bh0, acc2[mt][0], 0, 0, 0);
            acc2[mt][0] = __builtin_amdgcn_mfma_f32_16x16x32_bf16(zl, bh0, acc2[mt][0], 0, 0, 0);
            acc2[mt][0] = __builtin_amdgcn_mfma_f32_16x16x32_bf16(zh, bl0, acc2[mt][0], 0, 0, 0);
            acc2[mt][1] = __builtin_amdgcn_mfma_f32_16x16x32_bf16(zh, bh1, acc2[mt][1], 0, 0, 0);
            acc2[mt][1] = __builtin_amdgcn_mfma_f32_16x16x32_bf16(zl, bh1, acc2[mt][1], 0, 0, 0);
            acc2[mt][1] = __builtin_amdgcn_mfma_f32_16x16x32_bf16(zh, bl1, acc2[mt][1], 0, 0, 0);
        }
    }
    __syncthreads();   // ZH2/ZL2 reads done; SB may overwrite

    // ---------------- B2.5: stage matvec results to SB ---------------------
#pragma unroll
    for (int mt = 0; mt < 5; ++mt)
#pragma unroll
        for (int nt = 0; nt < 2; ++nt) {
            const int col = nq * 32 + nt * 16 + lr;
#pragma unroll
            for (int q = 0; q < 4; ++q) {
                const int nd  = lk * 4 + q;
                const int row = (mm * 5 + mt) * 16 + nd;
                const int boff = (row * 512 + col * 4) ^ (((row >> 2) & 3) << 4);
                *(float*)(LB + boff) = acc2[mt][nt][q];
            }
        }
    __syncthreads();

    // ---------------- phase C: softmaxes + combine + write out -------------
#pragma unroll
    for (int ii = 0; ii < 2; ++ii) {
        const int nd = w + ii * 8;
        const int n  = n0 + nd;
        const float nf = idn[n];

        v2f ar[5], dr[5];
#pragma unroll
        for (int r = 0; r < 5; ++r) {
            const int rowc = r * 16 + nd;
            const int rowd = (5 + r) * 16 + nd;
            const int bc = (rowc * 512 + l * 8) ^ (((rowc >> 2) & 3) << 4);
            const int bd = (rowd * 512 + l * 8) ^ (((rowd >> 2) & 3) << 4);
            ar[r] = *(const v2f*)(LB + bc) * nf;
            dr[r] = *(const v2f*)(LB + bd) * nf;
        }

        float pc[15], pd[15];
        {
            int k = 0;
#pragma unroll
            for (int r = 0; r < 5; ++r)
#pragma unroll
                for (int s = r; s < 5; ++s, ++k) {
                    v2f qc = ar[r] * ar[s];
                    v2f qd = dr[r] * dr[s];
                    float vc = qc.x + qc.y;
                    float vd = qd.x + qd.y;
#pragma unroll
                    for (int off = 32; off; off >>= 1) {
                        vc += __shfl_xor(vc, off);
                        vd += __shfl_xor(vd, off);
                    }
                    pc[k] = vc; pd[k] = vd;
                }
        }

        v2f zcom[5], zdis[5];
#pragma unroll
        for (int r = 0; r < 5; ++r) {
            float sc[5], m = -1e30f;
#pragma unroll
            for (int s = 0; s < 5; ++s) { sc[s] = pc[sidx(r, s)]; m = fmaxf(m, sc[s]); }
            float e[5], se = 0.f;
#pragma unroll
            for (int s = 0; s < 5; ++s) { e[s] = __expf(sc[s] - m); se += e[s]; }
            float inv = 1.f / se;
            v2f a2 = (v2f)0.f;
#pragma unroll
            for (int s = 0; s < 5; ++s) a2 += ar[s] * e[s];
            zcom[r] = a2 * inv;

            float qq = pd[sidx(r, r)];
            float sd[5], md = -1e30f;
#pragma unroll
            for (int s = 0; s < 5; ++s) { sd[s] = qq - pd[sidx(r, s)]; md = fmaxf(md, sd[s]); }
            float ed[5], sed = 0.f;
#pragma unroll
            for (int s = 0; s < 5; ++s) { ed[s] = __expf(sd[s] - md); sed += ed[s]; }
            float invd = 1.f / sed;
            v2f d2 = (v2f)0.f;
#pragma unroll
            for (int s = 0; s < 5; ++s) d2 += dr[s] * ed[s];
            zdis[r] = dr[r] - d2 * invd;       // sum_s a*(zd_r - zd_s)
        }

        v2f p2 = (v2f)0.f;
#pragma unroll
        for (int r = 0; r < 5; ++r) {
            p2 += (*(const v2f*)&att_w[r * 128 + 2 * l]) * zcom[r];
            p2 += (*(const v2f*)&att_w[640 + r * 128 + 2 * l]) * zdis[r];
        }
        float part = p2.x + p2.y;
#pragma unroll
        for (int off = 32; off; off >>= 1) part += __shfl_xor(part, off);
        const float beta = 1.f / (1.f + __expf(-(part + att_b[0])));
        const float omb  = 1.f - beta;

#pragma unroll
        for (int r = 0; r < 5; ++r) {
            v2f o = zcom[r] * beta + zdis[r] * omb;
            *(v2f*)&out[(size_t)n * 640 + r * 128 + 2 * l] = o;
        }
    }
}

// ============================ interaction (lean fallback) ===================
__global__ __launch_bounds__(512, 4) void interact2_kernel(
    float* __restrict__ z,
    const unsigned short* __restrict__ wct_h, const unsigned short* __restrict__ wct_l,
    const unsigned short* __restrict__ wdt_h, const unsigned short* __restrict__ wdt_l,
    const float* __restrict__ att_w, const float* __restrict__ att_b,
    const float* __restrict__ idn)
{
    __shared__ float SB[2 * 5 * 16 * 128];

    const int t  = threadIdx.x;
    const int w  = t >> 6;
    const int l  = t & 63;
    const int lr = l & 15;
    const int lk = l >> 4;
    const int n0 = blockIdx.x * 16;

    const int mm = w >> 2;
    const int nq = w & 3;
    const unsigned short* bhp = mm ? wdt_h : wct_h;
    const unsigned short* blp = mm ? wdt_l : wct_l;

    f32x4 acc[5][2];
#pragma unroll
    for (int mt = 0; mt < 5; ++mt) {
        acc[mt][0] = (f32x4){0.f, 0.f, 0.f, 0.f};
        acc[mt][1] = (f32x4){0.f, 0.f, 0.f, 0.f};
    }

#pragma unroll
    for (int mt = 0; mt < 5; ++mt) {
        bf16x8 ah[4], al[4];
        const float* ap = z + (size_t)(n0 + lr) * 640 + mt * 128 + lk * 8;
#pragma unroll
        for (int ks = 0; ks < 4; ++ks) {
            float4 v0 = *(const float4*)(ap + ks * 32);
            float4 v1 = *(const float4*)(ap + ks * 32 + 4);
            float f[8] = {v0.x, v0.y, v0.z, v0.w, v1.x, v1.y, v1.z, v1.w};
#pragma unroll
            for (int j = 0; j < 8; ++j) {
                unsigned short hi = f2b(f[j]);
                ah[ks][j] = (short)hi;
                al[ks][j] = (short)f2b(f[j] - b2f(hi));
            }
        }
#pragma unroll
        for (int nt = 0; nt < 2; ++nt) {
            const int col = nq * 32 + nt * 16 + lr;
#pragma unroll
            for (int ks = 0; ks < 4; ++ks) {
                bf16x8 vh = *(const bf16x8*)&bhp[(size_t)col * 128 + ks * 32 + lk * 8];
                bf16x8 vl = *(const bf16x8*)&blp[(size_t)col * 128 + ks * 32 + lk * 8];
                acc[mt][nt] = __builtin_amdgcn_mfma_f32_16x16x32_bf16(ah[ks], vh, acc[mt][nt], 0, 0, 0);
                acc[mt][nt] = __builtin_amdgcn_mfma_f32_16x16x32_bf16(al[ks], vh, acc[mt][nt], 0, 0, 0);
                acc[mt][nt] = __builtin_amdgcn_mfma_f32_16x16x32_bf16(ah[ks], vl, acc[mt][nt], 0, 0, 0);
            }
        }
    }

#pragma unroll
    for (int mt = 0; mt < 5; ++mt)
#pragma unroll
        for (int nt = 0; nt < 2; ++nt) {
            const int col = nq * 32 + nt * 16 + lr;
#pragma unroll
            for (int q = 0; q < 4; ++q) {
                const int nd = lk * 4 + q;
                SB[(((mm * 5 + mt) * 16) + nd) * 128 + col] = acc[mt][nt][q];
            }
        }
    __syncthreads();

#pragma unroll
    for (int ii = 0; ii < 2; ++ii) {
        const int nd = w + ii * 8;
        const int n  = n0 + nd;
        const float nf = idn[n];

        v2f ar[5], dr[5];
#pragma unroll
        for (int r = 0; r < 5; ++r) {
            ar[r] = *(const v2f*)&SB[((r * 16) + nd) * 128 + 2 * l] * nf;
            dr[r] = *(const v2f*)&SB[(((5 + r) * 16) + nd) * 128 + 2 * l] * nf;
        }

        float pc[15], pd[15];
        {
            int k = 0;
#pragma unroll
            for (int r = 0; r < 5; ++r)
#pragma unroll
                for (int s = r; s < 5; ++s, ++k) {
                    v2f qc = ar[r] * ar[s];
                    v2f qd = dr[r] * dr[s];
                    float vc = qc.x + qc.y;
                    float vd = qd.x + qd.y;
#pragma unroll
                    for (int off = 32; off; off >>= 1) {
                        vc += __shfl_xor(vc, off);
                        vd += __shfl_xor(vd, off);
                    }
                    pc[k] = vc; pd[k] = vd;
                }
        }

        v2f zcom[5], zdis[5];
#pragma unroll
        for (int r = 0; r < 5; ++r) {
            float sc[5], m = -1e30f;
#pragma unroll
            for (int s = 0; s < 5; ++s) { sc[s] = pc[sidx(r, s)]; m = fmaxf(m, sc[s]); }
            float e[5], se = 0.f;
#pragma unroll
            for (int s = 0; s < 5; ++s) { e[s] = __expf(sc[s] - m); se += e[s]; }
            float inv = 1.f / se;
            v2f a2 = (v2f)0.f;
#pragma unroll
            for (int s = 0; s < 5; ++s) a2 += ar[s] * e[s];
            zcom[r] = a2 * inv;

            float qq = pd[sidx(r, r)];
            float sd[5], md = -1e30f;
#pragma unroll
            for (int s = 0; s < 5; ++s) { sd[s] = qq - pd[sidx(r, s)]; md = fmaxf(md, sd[s]); }
            float ed[5], sed = 0.f;
#pragma unroll
            for (int s = 0; s < 5; ++s) { ed[s] = __expf(sd[s] - md); sed += ed[s]; }
            float invd = 1.f / sed;
            v2f d2 = (v2f)0.f;
#pragma unroll
            for (int s = 0; s < 5; ++s) d2 += dr[s] * ed[s];
            zdis[r] = dr[r] - d2 * invd;
        }

        v2f p2 = (v2f)0.f;
#pragma unroll
        for (int r = 0; r < 5; ++r) {
            p2 += (*(const v2f*)&att_w[r * 128 + 2 * l]) * zcom[r];
            p2 += (*(const v2f*)&att_w[640 + r * 128 + 2 * l]) * zdis[r];
        }
        float part = p2.x + p2.y;
#pragma unroll
        for (int off = 32; off; off >>= 1) part += __shfl_xor(part, off);
        const float beta = 1.f / (1.f + __expf(-(part + att_b[0])));
        const float omb  = 1.f - beta;

#pragma unroll
        for (int r = 0; r < 5; ++r) {
            v2f o = zcom[r] * beta + zdis[r] * omb;
            *(v2f*)&z[(size_t)n * 640 + r * 128 + 2 * l] = o;
        }
    }
}

// ============================ launch ========================================
extern "C" void kernel_launch(void* const* d_in, const int* in_sizes, int n_in,
                              void* d_out, int out_size, void* d_ws, size_t ws_size,
                              hipStream_t stream)
{
    const float* x      = (const float*)d_in[0];
    const float* W_self = (const float*)d_in[1];
    const float* W_ring = (const float*)d_in[2];
    const float* WC     = (const float*)d_in[3];
    const float* WD     = (const float*)d_in[4];
    const float* att_w  = (const float*)d_in[5];
    const float* att_b  = (const float*)d_in[6];
    const float* odn    = (const float*)d_in[7];
    const float* idn    = (const float*)d_in[8];
    const int*   rows   = (const int*)d_in[9];
    const int*   cols   = (const int*)d_in[10];
    float* out = (float*)d_out;

    // ---- workspace layout ----
    const size_t wb_sz  = (size_t)640 * 128 * 2;        // wh, wl
    const size_t wt_sz  = (size_t)128 * 128 * 2;        // wct_h/l, wdt_h/l
    const size_t y1_sz  = (size_t)NN * D * 4;           // 25.6 MB per ring
    const size_t cnt_sz = (size_t)RR * NN * 4;
    const size_t rp_sz  = (size_t)RR * (NN + 1) * 4;
    const size_t cur_sz = (size_t)RR * NN * 4;
    const size_t bs_sz  = 4096;
    const size_t pm_sz  = (size_t)RR * NNZ * 4;
    const size_t fixed  = 2 * wb_sz + 4 * wt_sz + cnt_sz + rp_sz + cur_sz + bs_sz + pm_sz;
    const bool big = ws_size >= fixed + RR * y1_sz + 4096;   // ~118.2 MB

    char* p = (char*)d_ws;
    unsigned short* wh    = (unsigned short*)p; p += wb_sz;
    unsigned short* wl    = (unsigned short*)p; p += wb_sz;
    unsigned short* wct_h = (unsigned short*)p; p += wt_sz;
    unsigned short* wct_l = (unsigned short*)p; p += wt_sz;
    unsigned short* wdt_h = (unsigned short*)p; p += wt_sz;
    unsigned short* wdt_l = (unsigned short*)p; p += wt_sz;
    float* y    = (float*)p; p += (big ? RR : 1) * y1_sz;
    int* cnt    = (int*)p; p += cnt_sz;
    int* rowptr = (int*)p; p += rp_sz;
    int* cursor = (int*)p; p += cur_sz;
    int* bsum   = (int*)p; p += bs_sz;
    int* perm   = (int*)p;

    // ---- weight conversions (tiny) ----
    convw_kernel<<<320, 256, 0, stream>>>(W_self, W_ring, wh, wl);
    convt_kernel<<<64, 256, 0, stream>>>(WC, WD, wct_h, wct_l, wdt_h, wdt_l);

    // ---- CSR build ----
    hipMemsetAsync(cnt, 0, cnt_sz, stream);
    hist_kernel<<<dim3(NNZ / 256, RR), 256, 0, stream>>>(rows, cnt);
    scanA_kernel<<<dim3(NCHUNK, RR), 256, 0, stream>>>(cnt, bsum);
    scanB_kernel<<<1, 256, 0, stream>>>(bsum);
    scanC_kernel<<<dim3(NCHUNK, RR), 256, 0, stream>>>(cnt, bsum, rowptr, cursor);
    fill_kernel<<<dim3(NNZ / 256, RR), 256, 0, stream>>>(rows, cols, cursor, perm);

    if (big) {
        // gather all rings from x, then one fused z-GEMM + interaction kernel
        gather2_kernel<<<dim3(NN / 4, RR), 256, 0, stream>>>(x, odn, rowptr, perm, y, 0);
        fused_kernel<<<NN / 16, 512, 0, stream>>>(x, y, wh, wl,
                                                  wct_h, wct_l, wdt_h, wdt_l,
                                                  att_w, att_b, idn, out);
    } else {
        // lean fallback (~41 MB): per-ring gather + GEMM into d_out, then interact
        gemm5_kernel<<<dim3(NN / 16, 1), 256, 0, stream>>>(x, y, wh, wl, out, 0, 0);
        for (int r = 0; r < RR; ++r) {
            gather2_kernel<<<dim3(NN / 4, 1), 256, 0, stream>>>(x, odn, rowptr, perm, y, r);
            gemm5_kernel<<<dim3(NN / 16, 1), 256, 0, stream>>>(x, y, wh, wl, out, r + 1, r);
        }
        interact2_kernel<<<NN / 16, 512, 0, stream>>>(out, wct_h, wct_l, wdt_h, wdt_l,
                                                      att_w, att_b, idn);
    }
}